// Round 9
// baseline (186.414 us; speedup 1.0000x reference)
//
#include <hip/hip_runtime.h>
#include <cmath>

// SoftmaxStable over N = 2^26 fp32 (256 MiB in, 256 MiB out).
//
// FUSED cooperative-style kernel; tree-arrival barrier, fence-free crossing,
// PLAIN phase-3 stores (round-9 change).
// Evidence ledger:
//  - Traffic optimal fused: FETCH 262 MB = compulsory (L3 absorbs the whole
//    phase-3 re-read), WRITE 262 MB. (r3,5,7,8)
//  - Barrier fixed in three confirmed steps: cg-sync acquire-spin storm (r5,
//    +88us), tree arrival vs serialized RMWs (r7, +66us, RTT~34ns),
//    per-block agent fences (r8, +32us).
//  - Remaining ~60us residue sits in phase 3 (~90us for L3-read + 262MB
//    write => writes at ~3 TB/s). fillBufferAligned proves PLAIN stores do
//    6.9 TB/s write-only; r0 k_out's nt stores ran 3.2 wr + 3.2 rd. Theory:
//    nontemporal-store path caps ~3.2 TB/s; the nt hint (originally for L3
//    preservation) is now pure cost since L3 absorbs the re-read anyway.
// Change: phase-3 output uses plain stores. Everything else identical to r8.
//
// Phases: 1) stream own 128 KB region, local (m, exp-sum);  tree barrier;
//         2) every block redundantly reduces G partials (atomic loads);
//         3) re-read own region (L3 hit, proven), PLAIN-store out.
// Target: ~41 (p1) + ~10 (bar+p2) + ~45-60 (p3) ~= 110-125 us.
// Falls back to the verified 3-kernel path (127 us) if coop launch fails.

typedef float f4v __attribute__((ext_vector_type(4)));

#define BLOCK 256
#define GMAX  2048      // 8 blocks/CU * 256 CU co-resident

// barrier layout (uints): 64 leaves padded to 32 uints (128 B) each,
// then root (own line), then flag 4 KB later (different TCC channel).
#define NLEAF    64
#define LEAF_PAD 32
#define ROOT_OFF (NLEAF * LEAF_PAD)
#define FLAG_OFF (ROOT_OFF + 1024)
#define BAR_UINTS (FLAG_OFF + 32)

// fallback (verified) config
#define NBLK  8192
#define ITERS 8

// Combine two (max, sum) states; fp32 __expf scale, fp64 sum.
// Guards m==mn so (-inf,-inf) never produces 0*inf or exp(nan).
__device__ __forceinline__ void combine(float& m, double& s, float m2, double s2) {
    float mn = fmaxf(m, m2);
    double e1 = (m  == mn) ? s  : s  * (double)__expf(m  - mn);
    double e2 = (m2 == mn) ? s2 : s2 * (double)__expf(m2 - mn);
    s = e1 + e2;
    m = mn;
}

__global__ void k_init(unsigned* __restrict__ bar) {
    for (int i = threadIdx.x; i < BAR_UINTS; i += blockDim.x) bar[i] = 0u;
}

__global__ __launch_bounds__(BLOCK, 8)
void k_fused(const f4v* __restrict__ x, f4v* __restrict__ o, int n4,
             double* __restrict__ ps, float* __restrict__ pm,
             unsigned* __restrict__ bar) {
    const int G      = gridDim.x;
    const int perBlk = n4 / G;              // f4 per block (exact, pow2 grid)
    const int ngrp   = perBlk >> 11;        // / (BLOCK * 8)
    const int base   = blockIdx.x * perBlk + threadIdx.x;

    // ---------------- phase 1: local (m, s) over own region ----------------
    float  m  = -INFINITY;
    double sd = 0.0;
    for (int g = 0; g < ngrp; ++g) {
        f4v v[8];
        const int gb = base + g * (BLOCK * 8);
#pragma unroll
        for (int j = 0; j < 8; ++j)
            v[j] = x[gb + j * BLOCK];
        float mg = -INFINITY;
#pragma unroll
        for (int j = 0; j < 8; ++j)
            mg = fmaxf(mg, fmaxf(fmaxf(v[j].x, v[j].y), fmaxf(v[j].z, v[j].w)));
        float sg = 0.f;
#pragma unroll
        for (int j = 0; j < 8; ++j)
            sg += __expf(v[j].x - mg) + __expf(v[j].y - mg)
                + __expf(v[j].z - mg) + __expf(v[j].w - mg);
        combine(m, sd, mg, (double)sg);
    }

    // ---------------- block reduce -> per-block partial ---------------------
    for (int off = 32; off > 0; off >>= 1) {
        float  m2 = __shfl_down(m,  off, 64);
        double s2 = __shfl_down(sd, off, 64);
        combine(m, sd, m2, s2);
    }
    __shared__ float  sm[BLOCK / 64];
    __shared__ double ss[BLOCK / 64];
    const int lane = threadIdx.x & 63;
    const int wid  = threadIdx.x >> 6;
    if (lane == 0) { sm[wid] = m; ss[wid] = sd; }
    __syncthreads();

    // --------- fence-free tree-arrival grid barrier -------------------------
    if (threadIdx.x == 0) {
        for (int w = 1; w < BLOCK / 64; ++w) combine(m, sd, sm[w], ss[w]);
        // Partials: agent-scope atomic stores -> coherence point, bypass L2.
        __hip_atomic_store(&ps[blockIdx.x], sd, __ATOMIC_RELAXED,
                           __HIP_MEMORY_SCOPE_AGENT);
        __hip_atomic_store(&pm[blockIdx.x], m,  __ATOMIC_RELAXED,
                           __HIP_MEMORY_SCOPE_AGENT);
        // Drain this thread's stores (no cache op; nothing is dirty).
        asm volatile("s_waitcnt vmcnt(0)" ::: "memory");
        const int nleaf  = (G >= NLEAF) ? NLEAF : G;   // both pow2
        const int leafSz = G / nleaf;
        unsigned* leafc  = &bar[(blockIdx.x & (nleaf - 1)) * LEAF_PAD];
        unsigned a = atomicAdd(leafc, 1u) + 1u;        // coherence-point RMW
        if (a == (unsigned)leafSz) {
            unsigned r = atomicAdd(&bar[ROOT_OFF], 1u) + 1u;
            if (r == (unsigned)nleaf)
                __hip_atomic_store(&bar[FLAG_OFF], 1u, __ATOMIC_RELAXED,
                                   __HIP_MEMORY_SCOPE_AGENT);
        }
        while (__hip_atomic_load(&bar[FLAG_OFF], __ATOMIC_RELAXED,
                                 __HIP_MEMORY_SCOPE_AGENT) == 0u)
            __builtin_amdgcn_s_sleep(8);               // relaxed spin
        asm volatile("" ::: "memory");                 // compiler barrier only
    }
    __syncthreads();   // exec+memory barrier: phase-2 loads stay behind spin

    // ------- every block redundantly reduces G partials (atomic loads) ------
    float  mf = -INFINITY;
    double sf = 0.0;
    for (int i = threadIdx.x; i < G; i += BLOCK) {
        float  m2 = __hip_atomic_load(&pm[i], __ATOMIC_RELAXED,
                                      __HIP_MEMORY_SCOPE_AGENT);
        double s2 = __hip_atomic_load(&ps[i], __ATOMIC_RELAXED,
                                      __HIP_MEMORY_SCOPE_AGENT);
        combine(mf, sf, m2, s2);
    }
    for (int off = 32; off > 0; off >>= 1) {
        float  m2 = __shfl_down(mf, off, 64);
        double s2 = __shfl_down(sf, off, 64);
        combine(mf, sf, m2, s2);
    }
    if (lane == 0) { sm[wid] = mf; ss[wid] = sf; }
    __syncthreads();
    __shared__ float fm, fi;
    if (threadIdx.x == 0) {
        for (int w = 1; w < BLOCK / 64; ++w) combine(mf, sf, sm[w], ss[w]);
        fm = mf;
        fi = (float)(1.0 / sf);
    }
    __syncthreads();
    const float M   = fm;
    const float INV = fi;

    // ------- phase 3: re-read own region (L3 hit) -> out, PLAIN stores -----
    for (int g = 0; g < ngrp; ++g) {
        f4v v[8];
        const int gb = base + g * (BLOCK * 8);
#pragma unroll
        for (int j = 0; j < 8; ++j)
            v[j] = x[gb + j * BLOCK];
#pragma unroll
        for (int j = 0; j < 8; ++j) {
            f4v r;
            r.x = __expf(v[j].x - M) * INV;
            r.y = __expf(v[j].y - M) * INV;
            r.z = __expf(v[j].z - M) * INV;
            r.w = __expf(v[j].w - M) * INV;
            o[gb + j * BLOCK] = r;    // plain store: full write-path BW
        }
    }
}

// ======================= fallback: verified 3-kernel path ==================

__global__ __launch_bounds__(BLOCK)
void k_partials(const f4v* __restrict__ x, long n4,
                double* __restrict__ ps, float* __restrict__ pm) {
    long base = (long)blockIdx.x * (BLOCK * ITERS) + threadIdx.x;
    f4v v[ITERS];
#pragma unroll
    for (int j = 0; j < ITERS; ++j) {
        long idx = base + (long)j * BLOCK;
        if (idx < n4) v[j] = x[idx];
        else          v[j] = (f4v){-INFINITY, -INFINITY, -INFINITY, -INFINITY};
    }
    float m = -INFINITY;
#pragma unroll
    for (int j = 0; j < ITERS; ++j)
        m = fmaxf(m, fmaxf(fmaxf(v[j].x, v[j].y), fmaxf(v[j].z, v[j].w)));
    float s = 0.f;
    if (m != -INFINITY) {
#pragma unroll
        for (int j = 0; j < ITERS; ++j)
            s += __expf(v[j].x - m) + __expf(v[j].y - m) +
                 __expf(v[j].z - m) + __expf(v[j].w - m);
    }
    double sd = (double)s;
    for (int off = 32; off > 0; off >>= 1) {
        float  m2 = __shfl_down(m,  off, 64);
        double s2 = __shfl_down(sd, off, 64);
        combine(m, sd, m2, s2);
    }
    __shared__ float  sm[BLOCK / 64];
    __shared__ double ss[BLOCK / 64];
    int lane = threadIdx.x & 63;
    int wid  = threadIdx.x >> 6;
    if (lane == 0) { sm[wid] = m; ss[wid] = sd; }
    __syncthreads();
    if (threadIdx.x == 0) {
        for (int w = 1; w < BLOCK / 64; ++w) combine(m, sd, sm[w], ss[w]);
        ps[blockIdx.x] = sd;
        pm[blockIdx.x] = m;
    }
}

__global__ __launch_bounds__(1024)
void k_reduce(const double* __restrict__ ps, const float* __restrict__ pm,
              int nblk, float* __restrict__ fin) {
    float  m = -INFINITY;
    double s = 0.0;
    for (int i = threadIdx.x; i < nblk; i += 1024) combine(m, s, pm[i], ps[i]);
    for (int off = 32; off > 0; off >>= 1) {
        float  m2 = __shfl_down(m, off, 64);
        double s2 = __shfl_down(s, off, 64);
        combine(m, s, m2, s2);
    }
    __shared__ float  sm[16];
    __shared__ double ss[16];
    int lane = threadIdx.x & 63;
    int wid  = threadIdx.x >> 6;
    if (lane == 0) { sm[wid] = m; ss[wid] = s; }
    __syncthreads();
    if (threadIdx.x == 0) {
        for (int w = 1; w < 16; ++w) combine(m, s, sm[w], ss[w]);
        fin[0] = m;
        fin[1] = (float)(1.0 / s);
    }
}

__global__ __launch_bounds__(BLOCK)
void k_out(const f4v* __restrict__ x, f4v* __restrict__ o, long n4,
           const float* __restrict__ fin) {
    float m   = fin[0];
    float inv = fin[1];
    long stride = (long)gridDim.x * BLOCK;
    for (long i = (long)blockIdx.x * BLOCK + threadIdx.x; i < n4; i += stride) {
        f4v v = x[i];
        f4v r;
        r.x = __expf(v.x - m) * inv;
        r.y = __expf(v.y - m) * inv;
        r.z = __expf(v.z - m) * inv;
        r.w = __expf(v.w - m) * inv;
        __builtin_nontemporal_store(r, &o[i]);
    }
}

extern "C" void kernel_launch(void* const* d_in, const int* in_sizes, int n_in,
                              void* d_out, int out_size, void* d_ws, size_t ws_size,
                              hipStream_t stream) {
    const f4v* x = (const f4v*)d_in[0];
    f4v* out = (f4v*)d_out;
    long n  = (long)in_sizes[0];
    long n4 = n / 4;                 // N = 2^26, exactly divisible
    int  n4i = (int)n4;

    // ws layout (fused):    [GMAX doubles ps][GMAX floats pm][BAR_UINTS bar]
    // ws layout (fallback): [NBLK doubles ps][NBLK floats pm][2 floats fin]
    // (overlap harmless: one path per launch, each fully overwrites its reads)
    double*   ps  = (double*)d_ws;
    float*    pm  = (float*)((char*)d_ws + NBLK * sizeof(double));
    float*    fin = (float*)((char*)d_ws + NBLK * (sizeof(double) + sizeof(float)));
    float*    pmf = (float*)((char*)d_ws + GMAX * sizeof(double));
    unsigned* bar = (unsigned*)((char*)d_ws + GMAX * (sizeof(double) + sizeof(float)));

    // One-time: clamp cooperative grid to co-resident capacity (pow2 so the
    // per-thread division stays exact). 0 => fallback path.
    static int g_grid = -1;
    if (g_grid < 0) {
        int nb = 0;
        if (hipOccupancyMaxActiveBlocksPerMultiprocessor(&nb, k_fused, BLOCK, 0)
                != hipSuccess) nb = 0;
        int dev = 0;
        (void)hipGetDevice(&dev);
        hipDeviceProp_t prop{};
        int cus = 256;
        if (hipGetDeviceProperties(&prop, dev) == hipSuccess && prop.multiProcessorCount > 0)
            cus = prop.multiProcessorCount;
        long cap = (long)nb * cus;
        if (cap >= 1) {
            int g = GMAX;
            while (g > 1 && g > cap) g >>= 1;
            g_grid = g;
        } else {
            g_grid = 0;
        }
    }

    bool done = false;
    if (g_grid > 0) {
        hipLaunchKernelGGL(k_init, dim3(1), dim3(256), 0, stream, bar);
        void* args[] = { (void*)&x, (void*)&out, (void*)&n4i,
                         (void*)&ps, (void*)&pmf, (void*)&bar };
        hipError_t err = hipLaunchCooperativeKernel((void*)k_fused, dim3(g_grid),
                                                    dim3(BLOCK), args, 0, stream);
        if (err == hipSuccess) {
            done = true;
        } else {
            (void)hipGetLastError();   // clear sticky error, fall back forever
            g_grid = 0;
        }
    }

    if (!done) {
        hipLaunchKernelGGL(k_partials, dim3(NBLK), dim3(BLOCK), 0, stream,
                           x, n4, ps, pm);
        hipLaunchKernelGGL(k_reduce, dim3(1), dim3(1024), 0, stream, ps, pm, NBLK, fin);
        hipLaunchKernelGGL(k_out, dim3(NBLK), dim3(BLOCK), 0, stream,
                           x, out, n4, fin);
    }
}